// Round 1
// 823.281 us; speedup vs baseline: 1.2142x; 1.2142x over previous
//
#include <hip/hip_runtime.h>
#include <hip/hip_bf16.h>

typedef __hip_bfloat16 bf16;
typedef __attribute__((ext_vector_type(8))) short bf16x8;   // 8 bf16 = 4 VGPRs
typedef __attribute__((ext_vector_type(4))) float f32x4;

#define TOK    1024
#define DIM    96
#define HIDN   384
#define HEADS  8
#define DH     768
#define INNER  6144
#define SEQ    512
#define NDEPTH 5
#define EPSLN  1e-5f
#define QSCALE 0.125f

__device__ __forceinline__ float b2f(bf16 v) { return __bfloat162float(v); }
__device__ __forceinline__ bf16  f2b(float v) { return __float2bfloat16(v); }

// Load element i from an external input buffer: f==1 -> bf16, f==0 -> fp32.
__device__ __forceinline__ float gload(const void* p, size_t i, int f) {
  return f ? b2f(((const bf16*)p)[i]) : ((const float*)p)[i];
}

// ---------------- dtype detector (bf16 vs fp32 external buffers) ------------
__global__ __launch_bounds__(256) void detect_kernel(const void* xraw, int* flag) {
  __shared__ int cnt[256];
  int t = threadIdx.x;
  const unsigned short* u = (const unsigned short*)xraw;
  int c = 0;
  #pragma unroll
  for (int i = 0; i < 4; i++) {
    unsigned short h = u[2 * (t * 4 + i)];
    int e = (h >> 7) & 0xFF;
    if (e >= 87 && e <= 132) c++;
  }
  cnt[t] = c;
  __syncthreads();
  for (int s = 128; s > 0; s >>= 1) {
    if (t < s) cnt[t] += cnt[t + s];
    __syncthreads();
  }
  if (t == 0) *flag = (cnt[0] > 700) ? 1 : 0;
}

// ---------------- cast input x -> fp32 ----------------
__global__ __launch_bounds__(256) void cast_kernel(const void* __restrict__ in,
                                                   float* __restrict__ out, int n,
                                                   const int* __restrict__ flagp) {
  int f = *flagp;
  int i = blockIdx.x * blockDim.x + threadIdx.x;
  if (i < n) out[i] = gload(in, i, f);
}

// ---------------- cast external weight -> bf16 copy (same layout) -----------
__global__ __launch_bounds__(256) void castw_kernel(const void* __restrict__ in,
                                                    bf16* __restrict__ out, int n,
                                                    const int* __restrict__ flagp) {
  int f = *flagp;
  int i0 = (blockIdx.x * blockDim.x + threadIdx.x) * 4;
  #pragma unroll
  for (int j = 0; j < 4; j++) {
    int i = i0 + j;
    if (i < n) out[i] = f2b(gload(in, i, f));
  }
}

// ---------------- weight transpose+convert: [bz][R][C] -> bf16 [bz][C][R] ---
__global__ __launch_bounds__(256) void wtrans_kernel(
    const void* __restrict__ src, int R, int C,
    bf16* __restrict__ dst, const int* __restrict__ flagp) {
  __shared__ float tile[32][33];
  int f = *flagp;
  int t = threadIdx.x;
  int tx = t & 31, ty = t >> 5;
  int c0 = blockIdx.x * 32, r0 = blockIdx.y * 32;
  size_t bb = (size_t)blockIdx.z * R * C;
  #pragma unroll
  for (int i = 0; i < 4; i++) {
    int r = r0 + ty + 8 * i, c = c0 + tx;
    float v = 0.f;
    if (r < R && c < C) v = gload(src, bb + (size_t)r * C + c, f);
    tile[ty + 8 * i][tx] = v;
  }
  __syncthreads();
  #pragma unroll
  for (int i = 0; i < 4; i++) {
    int cc = c0 + ty + 8 * i, rr = r0 + tx;
    if (cc < C && rr < R)
      dst[bb + (size_t)cc * R + rr] = f2b(tile[tx][ty + 8 * i]);
  }
}

// ---------------- LayerNorm over rows of length 96 ----------------
// Optionally also writes hnT: [b][96][512] bf16 transpose (for attention PV).
__global__ __launch_bounds__(256) void ln_kernel(
    const float* __restrict__ X, const void* __restrict__ gbase, size_t goff,
    void* __restrict__ outb, float* __restrict__ outf, bf16* __restrict__ hnT,
    int rows, int extout, const int* __restrict__ flagp) {
  int f = *flagp;
  const char* g = (const char*)gbase + goff * (size_t)(f ? 2 : 4);
  int row  = blockIdx.x * 4 + (threadIdx.x >> 6);
  int lane = threadIdx.x & 63;
  if (row >= rows) return;
  const float* xr = X + (size_t)row * DIM;
  float v0 = xr[lane];
  float v1 = (lane < 32) ? xr[64 + lane] : 0.f;
  float s = v0 + v1;
  #pragma unroll
  for (int off = 32; off > 0; off >>= 1) s += __shfl_xor(s, off);
  float mu = s * (1.f / 96.f);
  float d0 = v0 - mu;
  float d1 = (lane < 32) ? (v1 - mu) : 0.f;
  float q = d0 * d0 + d1 * d1;
  #pragma unroll
  for (int off = 32; off > 0; off >>= 1) q += __shfl_xor(q, off);
  float rstd = rsqrtf(q * (1.f / 96.f) + EPSLN);
  bool w32 = (extout && !f);
  float g0 = gload(g, lane, f) + 1.f;
  float o0 = d0 * rstd * g0;
  size_t base = (size_t)row * DIM;
  bf16* hT = nullptr;
  int ss = row & (SEQ - 1);
  if (hnT) hT = hnT + (size_t)(row >> 9) * DIM * SEQ;
  if (outb) {
    if (w32) ((float*)outb)[base + lane] = o0;
    else     ((bf16*)outb)[base + lane] = f2b(o0);
  }
  if (outf) outf[base + lane] = o0;
  if (hT) hT[(size_t)lane * SEQ + ss] = f2b(o0);
  if (lane < 32) {
    float g1 = gload(g, 64 + lane, f) + 1.f;
    float o1 = d1 * rstd * g1;
    if (outb) {
      if (w32) ((float*)outb)[base + 64 + lane] = o1;
      else     ((bf16*)outb)[base + 64 + lane] = f2b(o1);
    }
    if (outf) outf[base + 64 + lane] = o1;
    if (hT) hT[(size_t)(64 + lane) * SEQ + ss] = f2b(o1);
  }
}

// =================== MFMA GEMM body — BT form (B is bf16 [N][K]) ============
// Used only by mtgt (weight-folding prep). Block 256 = 4 waves (2x2).
template <int WM>
__device__ __forceinline__ void gemm_bt_body(
    const bf16* __restrict__ A, int lda,
    const bf16* __restrict__ Bt, int ldb,
    int m0, int n0, int kbeg, int kend, int Mtot, int N,
    float alpha, bf16* __restrict__ Cb, int ldc) {
  constexpr int TM = WM * 32;
  __shared__ bf16 As[TM][40];
  __shared__ bf16 Bs[128][40];
  int t = threadIdx.x;
  int lane = t & 63;
  int wave = t >> 6;
  int wm = (wave >> 1) * (WM * 16), wn = (wave & 1) * 64;
  f32x4 acc[WM][4];
  #pragma unroll
  for (int i = 0; i < WM; i++)
    #pragma unroll
    for (int j = 0; j < 4; j++) acc[i][j] = (f32x4){0.f, 0.f, 0.f, 0.f};

  int arow = t >> 2, aseg = (t & 3) * 8;

  for (int kb = kbeg; kb < kend; kb += 32) {
    if constexpr (TM >= 64) {
      #pragma unroll
      for (int i = 0; i < TM / 64; i++) {
        int gm = min(m0 + arow + i * 64, Mtot - 1);
        *(uint4*)&As[arow + i * 64][aseg] =
            *(const uint4*)(A + (size_t)gm * lda + kb + aseg);
      }
    } else {
      if (arow < TM) {
        int gm = min(m0 + arow, Mtot - 1);
        *(uint4*)&As[arow][aseg] =
            *(const uint4*)(A + (size_t)gm * lda + kb + aseg);
      }
    }
    #pragma unroll
    for (int i = 0; i < 2; i++) {
      int r = arow + i * 64;
      int gn = n0 + r;
      uint4 val = {0, 0, 0, 0};
      if (gn < N) val = *(const uint4*)(Bt + (size_t)gn * ldb + kb + aseg);
      *(uint4*)&Bs[r][aseg] = val;
    }
    __syncthreads();
    int fm = lane & 15, fq = (lane >> 4) * 8;
    bf16x8 af[WM], bfv[4];
    #pragma unroll
    for (int i = 0; i < WM; i++)
      af[i] = *(const bf16x8*)&As[wm + i * 16 + fm][fq];
    #pragma unroll
    for (int j = 0; j < 4; j++)
      bfv[j] = *(const bf16x8*)&Bs[wn + j * 16 + fm][fq];
    #pragma unroll
    for (int i = 0; i < WM; i++)
      #pragma unroll
      for (int j = 0; j < 4; j++)
        acc[i][j] = __builtin_amdgcn_mfma_f32_16x16x32_bf16(af[i], bfv[j], acc[i][j], 0, 0, 0);
    __syncthreads();
  }
  int col = lane & 15, rq = (lane >> 4) * 4;
  #pragma unroll
  for (int j = 0; j < 4; j++) {
    int gn = n0 + wn + j * 16 + col;
    if (gn >= N) continue;
    #pragma unroll
    for (int i = 0; i < WM; i++) {
      #pragma unroll
      for (int r = 0; r < 4; r++) {
        int gm = m0 + wm + i * 16 + rq + r;
        if (gm >= Mtot) continue;
        Cb[(size_t)gm * ldc + gn] = f2b(acc[i][j][r] * alpha);
      }
    }
  }
}

// ---- precompute Mt (z<120) and Gt (z>=120): grid (1, 2, 240) ---------------
__global__ __launch_bounds__(256) void mtgt_kernel(
    const bf16* __restrict__ wqB, const bf16* __restrict__ wkB,
    const bf16* __restrict__ wvB, const bf16* __restrict__ woT,
    bf16* __restrict__ Mt, bf16* __restrict__ Gt) {
  int z = blockIdx.z;
  bool isM = z < 120;
  int zz = isM ? z : z - 120;
  int L = zz >> 3, h = zz & 7;
  size_t wo = (size_t)L * DIM * INNER + (size_t)h * DH;
  const bf16* A  = isM ? (wkB + wo) : (woT + wo);
  const bf16* Bt = isM ? (wqB + wo) : (wvB + wo);
  bf16* C = (isM ? Mt : Gt) + (size_t)zz * DIM * DIM;
  gemm_bt_body<2>(A, INNER, Bt, INNER, blockIdx.y * 64, 0, 0, DH, DIM, DIM,
                  isM ? QSCALE : 1.f, C, DIM);
}

// ============== fused attention v3: t + S + softmax + (P@hn)@Gt^T ===========
// grid (16 q-tiles, 16 z=b*8+h). All B operands read directly from L2-resident
// global (hn, hnT, Mt, Gt); only t/Z, P and softmax partials go through LDS.
// Output atomicAdd into x (8 heads accumulate into the same rows).
__global__ __launch_bounds__(256) void fattn3_kernel(
    const bf16* __restrict__ hn,    // [1024][96]
    const bf16* __restrict__ hnT,   // [2][96][512]
    const bf16* __restrict__ MtL,   // [8][96][96]
    const bf16* __restrict__ GtL,   // [8][96][96]
    float* __restrict__ x) {
  __shared__ bf16 tP[32][520];      // normalized P (full 512 cols)
  __shared__ bf16 Zs[32][104];      // t (stage 1-2), then Z = P@hn (stage 3b)
  __shared__ float red[2][4][32];
  int tid = threadIdx.x, lane = tid & 63, wave = tid >> 6;
  int fm = lane & 15, fq = (lane >> 4) * 8;
  int col = lane & 15, rq = (lane >> 4) * 4;
  int mw = wave & 1, ng = wave >> 1;
  int z = blockIdx.y, b = z >> 3, h = z & 7;
  int m0 = blockIdx.x * 32;
  const bf16* hnB = hn + (size_t)b * SEQ * DIM;
  const bf16* hTB = hnT + (size_t)b * DIM * SEQ;
  const bf16* MtH = MtL + (size_t)h * DIM * DIM;
  const bf16* GtH = GtL + (size_t)h * DIM * DIM;

  // ---- stage 1: t = hn_tile[32x96] @ Mt^T ----
  {
    f32x4 acc1[3];
    #pragma unroll
    for (int j = 0; j < 3; j++) acc1[j] = (f32x4){0.f, 0.f, 0.f, 0.f};
    #pragma unroll
    for (int kb = 0; kb < 96; kb += 32) {
      bf16x8 af = *(const bf16x8*)(hnB + (size_t)(m0 + mw * 16 + fm) * DIM + kb + fq);
      #pragma unroll
      for (int j = 0; j < 3; j++) {
        bf16x8 bv = *(const bf16x8*)(MtH + (size_t)((3 * ng + j) * 16 + fm) * DIM + kb + fq);
        acc1[j] = __builtin_amdgcn_mfma_f32_16x16x32_bf16(af, bv, acc1[j], 0, 0, 0);
      }
    }
    #pragma unroll
    for (int j = 0; j < 3; j++)
      #pragma unroll
      for (int r = 0; r < 4; r++)
        Zs[mw * 16 + rq + r][(3 * ng + j) * 16 + col] = f2b(acc1[j][r]);
  }
  __syncthreads();

  // ---- stage 2: S = t @ hn^T (32 x 512); wave covers cols [128w,128w+128) --
  f32x4 acc2[2][8];
  #pragma unroll
  for (int i = 0; i < 2; i++)
    #pragma unroll
    for (int j = 0; j < 8; j++) acc2[i][j] = (f32x4){0.f, 0.f, 0.f, 0.f};
  #pragma unroll
  for (int kb = 0; kb < 96; kb += 32) {
    bf16x8 af0 = *(const bf16x8*)&Zs[fm][kb + fq];
    bf16x8 af1 = *(const bf16x8*)&Zs[16 + fm][kb + fq];
    bf16x8 bv[8];
    #pragma unroll
    for (int j = 0; j < 8; j++)
      bv[j] = *(const bf16x8*)(hnB + (size_t)(wave * 128 + j * 16 + fm) * DIM + kb + fq);
    #pragma unroll
    for (int j = 0; j < 8; j++) {
      acc2[0][j] = __builtin_amdgcn_mfma_f32_16x16x32_bf16(af0, bv[j], acc2[0][j], 0, 0, 0);
      acc2[1][j] = __builtin_amdgcn_mfma_f32_16x16x32_bf16(af1, bv[j], acc2[1][j], 0, 0, 0);
    }
  }

  // ---- softmax over 512 cols ----
  float rmax[2][4];
  #pragma unroll
  for (int i = 0; i < 2; i++)
    #pragma unroll
    for (int r = 0; r < 4; r++) {
      float m = -1e30f;
      #pragma unroll
      for (int j = 0; j < 8; j++) m = fmaxf(m, acc2[i][j][r]);
      rmax[i][r] = m;
    }
  #pragma unroll
  for (int s = 1; s < 16; s <<= 1)
    #pragma unroll
    for (int i = 0; i < 2; i++)
      #pragma unroll
      for (int r = 0; r < 4; r++)
        rmax[i][r] = fmaxf(rmax[i][r], __shfl_xor(rmax[i][r], s));
  if (col == 0)
    #pragma unroll
    for (int i = 0; i < 2; i++)
      #pragma unroll
      for (int r = 0; r < 4; r++) red[0][wave][i * 16 + rq + r] = rmax[i][r];
  __syncthreads();
  float rsum[2][4];
  #pragma unroll
  for (int i = 0; i < 2; i++)
    #pragma unroll
    for (int r = 0; r < 4; r++) {
      int row = i * 16 + rq + r;
      float gm = fmaxf(fmaxf(red[0][0][row], red[0][1][row]),
                       fmaxf(red[0][2][row], red[0][3][row]));
      float s = 0.f;
      #pragma unroll
      for (int j = 0; j < 8; j++) {
        float e = __expf(acc2[i][j][r] - gm);
        acc2[i][j][r] = e;
        s += e;
      }
      rsum[i][r] = s;
    }
  #pragma unroll
  for (int s = 1; s < 16; s <<= 1)
    #pragma unroll
    for (int i = 0; i < 2; i++)
      #pragma unroll
      for (int r = 0; r < 4; r++)
        rsum[i][r] += __shfl_xor(rsum[i][r], s);
  if (col == 0)
    #pragma unroll
    for (int i = 0; i < 2; i++)
      #pragma unroll
      for (int r = 0; r < 4; r++) red[1][wave][i * 16 + rq + r] = rsum[i][r];
  __syncthreads();

  // each wave writes its own normalized 128-col P chunk (no serialization)
  #pragma unroll
  for (int i = 0; i < 2; i++)
    #pragma unroll
    for (int r = 0; r < 4; r++) {
      int row = i * 16 + rq + r;
      float tot = red[1][0][row] + red[1][1][row] + red[1][2][row] + red[1][3][row];
      float inv = 1.f / tot;
      #pragma unroll
      for (int j = 0; j < 8; j++)
        tP[row][wave * 128 + j * 16 + col] = f2b(acc2[i][j][r] * inv);
    }
  __syncthreads();

  // ---- stage 3a: Z = P @ hnT^T (32 x 96), K = 512 ----
  f32x4 acc3[3];
  #pragma unroll
  for (int j = 0; j < 3; j++) acc3[j] = (f32x4){0.f, 0.f, 0.f, 0.f};
  #pragma unroll 4
  for (int kb = 0; kb < 512; kb += 32) {
    bf16x8 af = *(const bf16x8*)&tP[mw * 16 + fm][kb + fq];
    #pragma unroll
    for (int j = 0; j < 3; j++) {
      bf16x8 bv = *(const bf16x8*)(hTB + (size_t)((3 * ng + j) * 16 + fm) * SEQ + kb + fq);
      acc3[j] = __builtin_amdgcn_mfma_f32_16x16x32_bf16(af, bv, acc3[j], 0, 0, 0);
    }
  }
  __syncthreads();   // t in Zs dead; safe to overwrite
  #pragma unroll
  for (int j = 0; j < 3; j++)
    #pragma unroll
    for (int r = 0; r < 4; r++)
      Zs[mw * 16 + rq + r][(3 * ng + j) * 16 + col] = f2b(acc3[j][r]);
  __syncthreads();

  // ---- stage 3b: O = Z @ Gt^T (32 x 96), K = 96 ----
  f32x4 acc4[3];
  #pragma unroll
  for (int j = 0; j < 3; j++) acc4[j] = (f32x4){0.f, 0.f, 0.f, 0.f};
  #pragma unroll
  for (int kb = 0; kb < 96; kb += 32) {
    bf16x8 af = *(const bf16x8*)&Zs[mw * 16 + fm][kb + fq];
    #pragma unroll
    for (int j = 0; j < 3; j++) {
      bf16x8 bv = *(const bf16x8*)(GtH + (size_t)((3 * ng + j) * 16 + fm) * DIM + kb + fq);
      acc4[j] = __builtin_amdgcn_mfma_f32_16x16x32_bf16(af, bv, acc4[j], 0, 0, 0);
    }
  }
  #pragma unroll
  for (int j = 0; j < 3; j++) {
    int gn = (3 * ng + j) * 16 + col;
    #pragma unroll
    for (int r = 0; r < 4; r++) {
      int gr = b * SEQ + m0 + mw * 16 + rq + r;
      atomicAdd(x + (size_t)gr * DIM + gn, acc4[j][r]);
    }
  }
}

// ====== fused MLP: [gmid-LN] + LN + GEMM1 + GELU + GEMM2 + bias + residual ==
// grid (32): each block owns 32 rows of x exclusively (no atomics, no splitK).
__global__ __launch_bounds__(256) void fmlp_kernel(
    float* __restrict__ X,
    const void* __restrict__ gmidb, size_t gmidoff, int useMid,
    const void* __restrict__ gmb, size_t gmoff,
    const bf16* __restrict__ w1T,   // [384][96]
    const void* __restrict__ b1b, size_t b1off,
    const bf16* __restrict__ w2T,   // [96][384]
    const void* __restrict__ b2b, size_t b2off,
    const int* __restrict__ flagp) {
  __shared__ float X1s[32][96];     // residual basis (post-gmid-LN if useMid)
  __shared__ bf16 As[32][104];      // LN2 output (GEMM1 A)
  __shared__ bf16 Hs[32][392];      // GELU hidden (GEMM2 A)
  int f = *flagp;
  int tid = threadIdx.x, lane = tid & 63, wave = tid >> 6;
  int fm = lane & 15, fq = (lane >> 4) * 8;
  int col = lane & 15, rq = (lane >> 4) * 4;
  int m0 = blockIdx.x * 32;
  const char* gm = (const char*)gmb + gmoff * (size_t)(f ? 2 : 4);
  float gm0 = gload(gm, lane, f) + 1.f;
  float gm1 = (lane < 32) ? (gload(gm, 64 + lane, f) + 1.f) : 0.f;
  float gd0 = 1.f, gd1 = 1.f;
  if (useMid) {
    const char* gmid = (const char*)gmidb + gmidoff * (size_t)(f ? 2 : 4);
    gd0 = gload(gmid, lane, f) + 1.f;
    gd1 = (lane < 32) ? (gload(gmid, 64 + lane, f) + 1.f) : 0.f;
  }
  for (int r = wave; r < 32; r += 4) {
    const float* xr = X + (size_t)(m0 + r) * DIM;
    float v0 = xr[lane];
    float v1 = (lane < 32) ? xr[64 + lane] : 0.f;
    if (useMid) {
      float s = v0 + v1;
      #pragma unroll
      for (int off = 32; off > 0; off >>= 1) s += __shfl_xor(s, off);
      float mu = s * (1.f / 96.f);
      float d0 = v0 - mu;
      float d1 = (lane < 32) ? (v1 - mu) : 0.f;
      float q = d0 * d0 + d1 * d1;
      #pragma unroll
      for (int off = 32; off > 0; off >>= 1) q += __shfl_xor(q, off);
      float rstd = rsqrtf(q * (1.f / 96.f) + EPSLN);
      v0 = d0 * rstd * gd0;
      v1 = (lane < 32) ? (d1 * rstd * gd1) : 0.f;
    }
    X1s[r][lane] = v0;
    if (lane < 32) X1s[r][64 + lane] = v1;
    float s = v0 + v1;
    #pragma unroll
    for (int off = 32; off > 0; off >>= 1) s += __shfl_xor(s, off);
    float mu = s * (1.f / 96.f);
    float d0 = v0 - mu;
    float d1 = (lane < 32) ? (v1 - mu) : 0.f;
    float q = d0 * d0 + d1 * d1;
    #pragma unroll
    for (int off = 32; off > 0; off >>= 1) q += __shfl_xor(q, off);
    float rstd = rsqrtf(q * (1.f / 96.f) + EPSLN);
    As[r][lane] = f2b(d0 * rstd * gm0);
    if (lane < 32) As[r][64 + lane] = f2b(d1 * rstd * gm1);
  }
  __syncthreads();

  // ---- GEMM1: [32x96] @ W1 -> [32x384], bias + exact GELU ----
  int mw = wave & 1, nh = wave >> 1;     // nh in {0,1}: cols nh*192..
  f32x4 acc1[12];
  #pragma unroll
  for (int j = 0; j < 12; j++) acc1[j] = (f32x4){0.f, 0.f, 0.f, 0.f};
  #pragma unroll
  for (int kb = 0; kb < 96; kb += 32) {
    bf16x8 af = *(const bf16x8*)&As[mw * 16 + fm][kb + fq];
    #pragma unroll
    for (int j = 0; j < 12; j++) {
      bf16x8 bv = *(const bf16x8*)(w1T + (size_t)(nh * 192 + j * 16 + fm) * DIM + kb + fq);
      acc1[j] = __builtin_amdgcn_mfma_f32_16x16x32_bf16(af, bv, acc1[j], 0, 0, 0);
    }
  }
  const char* b1p = (const char*)b1b + b1off * (size_t)(f ? 2 : 4);
  #pragma unroll
  for (int j = 0; j < 12; j++) {
    int gn = nh * 192 + j * 16 + col;
    float bv = gload(b1p, gn, f);
    #pragma unroll
    for (int r = 0; r < 4; r++) {
      float v = acc1[j][r] + bv;
      v = 0.5f * v * (1.f + erff(v * 0.70710678118f));
      Hs[mw * 16 + rq + r][gn] = f2b(v);
    }
  }
  __syncthreads();

  // ---- GEMM2: [32x384] @ W2 -> [32x96], bias + residual, direct store ----
  int ng = wave >> 1;
  f32x4 acc2[3];
  #pragma unroll
  for (int j = 0; j < 3; j++) acc2[j] = (f32x4){0.f, 0.f, 0.f, 0.f};
  #pragma unroll 4
  for (int kb = 0; kb < 384; kb += 32) {
    bf16x8 af = *(const bf16x8*)&Hs[mw * 16 + fm][kb + fq];
    #pragma unroll
    for (int j = 0; j < 3; j++) {
      bf16x8 bv = *(const bf16x8*)(w2T + (size_t)((3 * ng + j) * 16 + fm) * HIDN + kb + fq);
      acc2[j] = __builtin_amdgcn_mfma_f32_16x16x32_bf16(af, bv, acc2[j], 0, 0, 0);
    }
  }
  const char* b2p = (const char*)b2b + b2off * (size_t)(f ? 2 : 4);
  #pragma unroll
  for (int j = 0; j < 3; j++) {
    int gn = (3 * ng + j) * 16 + col;
    float bb = gload(b2p, gn, f);
    #pragma unroll
    for (int r = 0; r < 4; r++) {
      int gmr = m0 + mw * 16 + rq + r;
      X[(size_t)gmr * DIM + gn] = X1s[mw * 16 + rq + r][gn] + acc2[j][r] + bb;
    }
  }
}

// ---------------- host-side orchestration ----------------
extern "C" void kernel_launch(void* const* d_in, const int* in_sizes, int n_in,
                              void* d_out, int out_size, void* d_ws, size_t ws_size,
                              hipStream_t stream) {
  const void* in_x    = d_in[0];
  const void* gam_a   = d_in[1];
  const void* Wq      = d_in[2];
  const void* Wk      = d_in[3];
  const void* Wv      = d_in[4];
  const void* Wo      = d_in[5];
  const void* gam_m   = d_in[6];
  const void* W1      = d_in[7];
  const void* b1      = d_in[8];
  const void* W2      = d_in[9];
  const void* b2      = d_in[10];
  const void* gam_mid = d_in[11];
  const void* gam_fin = d_in[12];

  char* wsb = (char*)d_ws;
  size_t off = 0;
  auto carve = [&](size_t bytes) {
    char* p = wsb + off;
    off += (bytes + 255) & ~(size_t)255;
    return p;
  };
  int*   flag = (int*)carve(256);
  float* x    = (float*)carve((size_t)TOK * DIM * 4);
  bf16*  hn   = (bf16*)carve((size_t)TOK * DIM * 2);
  bf16*  hnT  = (bf16*)carve((size_t)2 * DIM * SEQ * 2);
  const size_t WSZ = (size_t)15 * DIM * INNER;   // per big weight, elements
  bf16*  wqB  = (bf16*)carve(WSZ * 2);
  bf16*  wkB  = (bf16*)carve(WSZ * 2);
  bf16*  wvB  = (bf16*)carve(WSZ * 2);
  bf16*  woT  = (bf16*)carve(WSZ * 2);
  bf16*  w1T  = (bf16*)carve((size_t)10 * DIM * HIDN * 2);
  bf16*  w2T  = (bf16*)carve((size_t)10 * DIM * HIDN * 2);
  bf16*  Mt   = (bf16*)carve((size_t)120 * DIM * DIM * 2);
  bf16*  Gt   = (bf16*)carve((size_t)120 * DIM * DIM * 2);

  detect_kernel<<<dim3(1), dim3(256), 0, stream>>>(in_x, flag);
  cast_kernel<<<dim3((TOK * DIM + 255) / 256), dim3(256), 0, stream>>>(in_x, x, TOK * DIM, flag);

  // ---- once-per-call weight prep ----
  int nW = (int)WSZ;
  castw_kernel<<<dim3((nW / 4 + 255) / 256), dim3(256), 0, stream>>>(Wq, wqB, nW, flag);
  castw_kernel<<<dim3((nW / 4 + 255) / 256), dim3(256), 0, stream>>>(Wk, wkB, nW, flag);
  castw_kernel<<<dim3((nW / 4 + 255) / 256), dim3(256), 0, stream>>>(Wv, wvB, nW, flag);
  wtrans_kernel<<<dim3(3, 192, 15), dim3(256), 0, stream>>>(Wo, INNER, DIM, woT, flag);
  wtrans_kernel<<<dim3(12, 3, 10), dim3(256), 0, stream>>>(W1, DIM, HIDN, w1T, flag);
  wtrans_kernel<<<dim3(3, 12, 10), dim3(256), 0, stream>>>(W2, HIDN, DIM, w2T, flag);
  mtgt_kernel<<<dim3(1, 2, 240), dim3(256), 0, stream>>>(wqB, wkB, wvB, woT, Mt, Gt);

  auto attn = [&](int d, int j) {
    size_t gi = ((size_t)d * 3 + j);
    const bf16* MtLp = Mt + gi * 8 * DIM * DIM;
    const bf16* GtLp = Gt + gi * 8 * DIM * DIM;
    ln_kernel<<<dim3(TOK / 4), dim3(256), 0, stream>>>(
        x, gam_a, gi * DIM, hn, nullptr, hnT, TOK, 0, flag);
    fattn3_kernel<<<dim3(16, 16), dim3(256), 0, stream>>>(hn, hnT, MtLp, GtLp, x);
  };

  auto mlp = [&](int d, int i) {
    size_t gi = ((size_t)d * 2 + i);
    fmlp_kernel<<<dim3(32), dim3(256), 0, stream>>>(
        x, gam_mid, (size_t)d * DIM, (i == 1) ? 1 : 0,
        gam_m, gi * DIM,
        w1T + gi * (size_t)DIM * HIDN, b1, gi * HIDN,
        w2T + gi * (size_t)DIM * HIDN, b2, gi * DIM, flag);
  };

  for (int d = 0; d < NDEPTH; d++) {
    attn(d, 0);
    mlp(d, 0);
    attn(d, 1);
    attn(d, 2);
    mlp(d, 1);   // includes the bare mid-LayerNorm (useMid=1)
  }
  ln_kernel<<<dim3(TOK / 4), dim3(256), 0, stream>>>(
      x, gam_fin, 0, d_out, nullptr, nullptr, TOK, 1, flag);
}